// Round 6
// baseline (237.906 us; speedup 1.0000x reference)
//
#include <hip/hip_runtime.h>
#include <hip/hip_bf16.h>

// TreeLSTM on MI355X — round 18: R17 structure + layer-offset bugfix.
// R17 post-mortem: leafwx applied the layer offset to BgX TWICE (once via the
// BX pointer, once in the index) -> layer-1 leaf gates used garbage weights ->
// h absmax 0.43, c absmax 468 (compounds ~2x/level up the 9-level chain).
// Fix: single offset. Structure unchanged:
//  - leafwx (2048 blocks, barrier-free): leaf h,c for both layers via 3-gate
//    GEMM (f unused at leaves; c=i*u), writes bf16 leaf h/c to global.
//  - forest: internal nodes only, flat 255-row LDS heap, 8 barrier intervals:
//    d7 = 8 independent tiles reading leaf h/c from GLOBAL, then d6..d0 in LDS.
//  - pack_b: weights + internal-row x->bf16 only.

#define TS 511
#define NT 128

typedef __attribute__((ext_vector_type(8))) short short8;
typedef __attribute__((ext_vector_type(4))) float floatx4;

#define MFMA_B16 __builtin_amdgcn_mfma_f32_16x16x32_bf16

// LDS-only barrier: LDS writes visible, global loads NOT drained.
#define BARLDS() do { \
    asm volatile("s_waitcnt lgkmcnt(0)" ::: "memory"); \
    __builtin_amdgcn_s_barrier(); \
    asm volatile("" ::: "memory"); \
} while (0)

__device__ __forceinline__ unsigned short f2b(float f) {
    return __builtin_bit_cast(unsigned short, __float2bfloat16(f));
}
__device__ __forceinline__ float b2f_u(unsigned short u) {
    unsigned v = (unsigned)u << 16;
    return __builtin_bit_cast(float, v);
}
__device__ __forceinline__ float rcp_(float x) { return __builtin_amdgcn_rcpf(x); }
__device__ __forceinline__ float sig_(float x) { return rcp_(1.0f + __expf(-x)); }
__device__ __forceinline__ float tanh_(float x) {
    float a = fabsf(x);
    float t = __expf(-2.0f * a);
    return copysignf((1.0f - t) * rcp_(1.0f + t), x);
}

// ---------------- weight packing + internal-x conversion ----------------
// BgU/BgX[(l*512+col)*128+kp] col-major: cols 0..383 = Uiou/Wiou (i|o|u),
//   384..511 = Uf/Wf. bp5[(l*5+g)*128+o]. xb[(tree*255+heap)*128+k]: bf16 x of
//   internal rows (heap 0..254).
__global__ void pack_b(const float* __restrict__ Wiou, const float* __restrict__ biou,
                       const float* __restrict__ Uiou, const float* __restrict__ Wf,
                       const float* __restrict__ bfv, const float* __restrict__ Uf,
                       const float* __restrict__ feat,
                       unsigned short* __restrict__ BgU, unsigned short* __restrict__ BgX,
                       float* __restrict__ bp5, unsigned short* __restrict__ xb) {
    int tid = blockIdx.x * 256 + threadIdx.x;   // 0..784383
    if (tid < 1280) {
        int l = tid / 640, r = tid % 640, g = r >> 7, o = r & 127;
        bp5[tid] = (g < 3) ? biou[l * 384 + r] : bfv[l * 128 + o];
    }
    if (tid < 131072) {
        int l = tid >> 16, r = tid & 65535, col = r >> 7, kp = r & 127;
        float v = (col < 384) ? Uiou[(l * 384 + col) * 128 + kp]
                              : Uf[(l * 128 + (col - 384)) * 128 + kp];
        BgU[((size_t)(l * 512 + col)) * 128 + kp] = f2b(v);
    } else if (tid < 262144) {
        int e2 = tid - 131072;
        int l = e2 >> 16, r = e2 & 65535, col = r >> 7, kp = r & 127;
        float v = (col < 384) ? Wiou[(l * 384 + col) * 128 + kp]
                              : Wf[(l * 128 + (col - 384)) * 128 + kp];
        BgX[((size_t)(l * 512 + col)) * 128 + kp] = f2b(v);
    } else {
        int e = tid - 262144;                  // 0..522239: internal x rows
        int tree = e / 4080;                   // 255 rows * 16 chunks
        int rem = e - tree * 4080;
        int row = rem >> 4, c8 = (rem & 15) * 8;
        const float* src = feat + ((size_t)tree * TS + row) * 128 + c8;
        float4 v0 = *(const float4*)src;
        float4 v1 = *(const float4*)(src + 4);
        short8 r;
        r[0] = (short)f2b(v0.x); r[1] = (short)f2b(v0.y);
        r[2] = (short)f2b(v0.z); r[3] = (short)f2b(v0.w);
        r[4] = (short)f2b(v1.x); r[5] = (short)f2b(v1.y);
        r[6] = (short)f2b(v1.z); r[7] = (short)f2b(v1.w);
        *(short8*)(xb + ((size_t)tree * 255 + row) * 128 + c8) = r;
    }
}

// ---------------- bulk leaf kernel (both layers, barrier-free) ----------------
// hb/cb[(l*32768 + tree*256 + leafidx)*128 + feat] bf16; leafidx = heap-255.
__global__ __launch_bounds__(256) void leafwx(
        const float* __restrict__ feat, const unsigned short* __restrict__ BgX,
        const float* __restrict__ bp5,
        unsigned short* __restrict__ hb, unsigned short* __restrict__ cb) {
    const int tid = threadIdx.x;
    const int lane = tid & 63, wave = tid >> 6;
    const int W = blockIdx.x * 4 + wave;       // 0..8191
    const int wn = W & 3;                      // 32-feat col group
    const int mt = W >> 2;                     // 0..2047
    const int l = mt >> 10, m = mt & 1023;     // layer, 32-leaf-row tile
    const int quad = lane >> 4, l15 = lane & 15;
    const unsigned short* BX = BgX + (size_t)l * 512 * 128;

    floatx4 acc[2][6];
#pragma unroll
    for (int mi = 0; mi < 2; mi++)
#pragma unroll
        for (int ni = 0; ni < 6; ni++)
            acc[mi][ni] = (floatx4){0.f, 0.f, 0.f, 0.f};

#pragma unroll
    for (int kb = 0; kb < 4; kb++) {
        short8 bfr[6];
#pragma unroll
        for (int ni = 0; ni < 6; ni++) {
            int col = (ni >> 1) * 128 + wn * 32 + (ni & 1) * 16 + l15;
            // FIX (R17 bug): BX already carries the layer offset — index by col only.
            bfr[ni] = *(const short8*)(BX + (size_t)col * 128 + kb * 32 + quad * 8);
        }
#pragma unroll
        for (int mi = 0; mi < 2; mi++) {
            int j = m * 32 + mi * 16 + l15;          // leaf row 0..32767
            int tree = j >> 8, li = j & 255;
            const float* p = feat + ((size_t)tree * TS + 255 + li) * 128 + kb * 32 + quad * 8;
            float4 u0 = *(const float4*)p;
            float4 u1 = *(const float4*)(p + 4);
            short8 a;
            a[0] = (short)f2b(u0.x); a[1] = (short)f2b(u0.y);
            a[2] = (short)f2b(u0.z); a[3] = (short)f2b(u0.w);
            a[4] = (short)f2b(u1.x); a[5] = (short)f2b(u1.y);
            a[6] = (short)f2b(u1.z); a[7] = (short)f2b(u1.w);
#pragma unroll
            for (int ni = 0; ni < 6; ni++)
                acc[mi][ni] = MFMA_B16(a, bfr[ni], acc[mi][ni], 0, 0, 0);
        }
    }
#pragma unroll
    for (int mi = 0; mi < 2; mi++)
#pragma unroll
        for (int ch = 0; ch < 2; ch++) {
            int of = wn * 32 + ch * 16 + l15;
            float bi = bp5[l * 640 + of];
            float bo = bp5[l * 640 + 128 + of];
            float bu = bp5[l * 640 + 256 + of];
#pragma unroll
            for (int r = 0; r < 4; r++) {
                int j = m * 32 + mi * 16 + quad * 4 + r;
                int tree = j >> 8, li = j & 255;
                float iv = sig_(acc[mi][ch][r] + bi);
                float ov = sig_(acc[mi][2 + ch][r] + bo);
                float uv = tanh_(acc[mi][4 + ch][r] + bu);
                float cn = iv * uv;
                float hn = ov * tanh_(cn);
                size_t idx = ((size_t)(l * 32768) + tree * 256 + li) * 128 + of;
                hb[idx] = f2b(hn);
                cb[idx] = f2b(cn);
            }
        }
}

// ---------------- forest: internal nodes only, 8 barrier intervals ----------------
// LDS: flat heap rows 0..254: h @ S[heap*136], c @ S[HC0 + heap*136].
__global__ __launch_bounds__(512) void forest(
        const unsigned short* __restrict__ xb16, const unsigned short* __restrict__ hbL,
        const unsigned short* __restrict__ cbL, const unsigned short* __restrict__ BgU,
        const unsigned short* __restrict__ BgX, const float* __restrict__ bp5,
        float* __restrict__ out) {
    __shared__ __align__(16) unsigned short S[69360];
    const int HC0 = 34680;

    const int tid = threadIdx.x;
    const int l = blockIdx.x >> 7, tree = blockIdx.x & 127;
    const int lane = tid & 63, w = tid >> 6;
    const int quad = lane >> 4, l15 = lane & 15;
    const int o = w * 16 + l15;
    const unsigned short* xb = xb16 + (size_t)tree * 255 * 128;
    const unsigned short* lh = hbL + ((size_t)(l * 32768) + tree * 256) * 128;
    const unsigned short* lc = cbL + ((size_t)(l * 32768) + tree * 256) * 128;
    const unsigned short* BU = BgU + (size_t)l * 512 * 128;
    const unsigned short* BX = BgX + (size_t)l * 512 * 128;

    float bb[5];
#pragma unroll
    for (int g = 0; g < 5; g++) bb[g] = bp5[l * 640 + g * 128 + o];

    // B fragment loads inline (compiler hoists/remats within the 128-VGPR cap)
    auto bu_ = [&](int g, int k) -> short8 {
        return *(const short8*)(BU + ((size_t)(g * 128 + o)) * 128 + k * 32 + quad * 8);
    };
    auto bx_ = [&](int g, int k) -> short8 {
        return *(const short8*)(BX + ((size_t)(g * 128 + o)) * 128 + k * 32 + quad * 8);
    };
    auto ldx = [&](int heap, int k) -> short8 {   // internal-node x (bf16)
        return *(const short8*)(xb + (size_t)heap * 128 + k * 32 + quad * 8);
    };

    // d7 tile t: 16 nodes heap 127+16t+idx, children = leaves (GLOBAL h/c)
    auto itile_g = [&](int t) {
        const int nA = 127 + t * 16 + l15;         // this lane's A-row node
        const int li0 = 32 * t + 2 * l15;          // its child0 leaf index
        short8 ax[4];
#pragma unroll
        for (int k = 0; k < 4; k++) ax[k] = ldx(nA, k);
        floatx4 ai = (floatx4){0.f, 0.f, 0.f, 0.f};
        floatx4 ao = ai, au = ai, awx = ai, af0 = ai, af1 = ai;
#pragma unroll
        for (int k = 0; k < 4; k++) {
            short8 h0 = *(const short8*)(lh + (size_t)li0 * 128 + k * 32 + quad * 8);
            short8 h1 = *(const short8*)(lh + (size_t)(li0 + 1) * 128 + k * 32 + quad * 8);
            ai = MFMA_B16(h0, bu_(0, k), ai, 0, 0, 0);
            ai = MFMA_B16(h1, bu_(0, k), ai, 0, 0, 0);
            ao = MFMA_B16(h0, bu_(1, k), ao, 0, 0, 0);
            ao = MFMA_B16(h1, bu_(1, k), ao, 0, 0, 0);
            au = MFMA_B16(h0, bu_(2, k), au, 0, 0, 0);
            au = MFMA_B16(h1, bu_(2, k), au, 0, 0, 0);
            af0 = MFMA_B16(h0, bu_(3, k), af0, 0, 0, 0);
            af1 = MFMA_B16(h1, bu_(3, k), af1, 0, 0, 0);
            ai = MFMA_B16(ax[k], bx_(0, k), ai, 0, 0, 0);
            ao = MFMA_B16(ax[k], bx_(1, k), ao, 0, 0, 0);
            au = MFMA_B16(ax[k], bx_(2, k), au, 0, 0, 0);
            awx = MFMA_B16(ax[k], bx_(3, k), awx, 0, 0, 0);
        }
#pragma unroll
        for (int r = 0; r < 4; r++) {
            int idx = quad * 4 + r;
            int node = 127 + t * 16 + idx;
            int lic = 32 * t + 2 * idx;
            float iv = sig_(ai[r] + bb[0]);
            float ov = sig_(ao[r] + bb[1]);
            float uv = tanh_(au[r] + bb[2]);
            float f0 = sig_(awx[r] + af0[r] + bb[3]);
            float f1 = sig_(awx[r] + af1[r] + bb[4]);
            float c0 = b2f_u(lc[(size_t)lic * 128 + o]);
            float c1 = b2f_u(lc[(size_t)(lic + 1) * 128 + o]);
            float cn = iv * uv + f0 * c0 + f1 * c1;
            float hn = ov * tanh_(cn);
            S[node * 136 + o] = f2b(hn);
            S[HC0 + node * 136 + o] = f2b(cn);
        }
    };

    // internal tile with LDS children: 16 nodes heap base+idx (idx<nv)
    auto itile_l = [&](int base, int nv, bool isRoot) {
        const int rl = (l15 < nv) ? l15 : nv - 1;
        const int nA = base + rl;
        const int ch0 = 2 * nA + 1;
        short8 ax[4];
#pragma unroll
        for (int k = 0; k < 4; k++) ax[k] = ldx(nA, k);
        floatx4 ai = (floatx4){0.f, 0.f, 0.f, 0.f};
        floatx4 ao = ai, au = ai, awx = ai, af0 = ai, af1 = ai;
#pragma unroll
        for (int k = 0; k < 4; k++) {
            short8 h0 = *(const short8*)&S[ch0 * 136 + k * 32 + quad * 8];
            short8 h1 = *(const short8*)&S[(ch0 + 1) * 136 + k * 32 + quad * 8];
            ai = MFMA_B16(h0, bu_(0, k), ai, 0, 0, 0);
            ai = MFMA_B16(h1, bu_(0, k), ai, 0, 0, 0);
            ao = MFMA_B16(h0, bu_(1, k), ao, 0, 0, 0);
            ao = MFMA_B16(h1, bu_(1, k), ao, 0, 0, 0);
            au = MFMA_B16(h0, bu_(2, k), au, 0, 0, 0);
            au = MFMA_B16(h1, bu_(2, k), au, 0, 0, 0);
            af0 = MFMA_B16(h0, bu_(3, k), af0, 0, 0, 0);
            af1 = MFMA_B16(h1, bu_(3, k), af1, 0, 0, 0);
            ai = MFMA_B16(ax[k], bx_(0, k), ai, 0, 0, 0);
            ao = MFMA_B16(ax[k], bx_(1, k), ao, 0, 0, 0);
            au = MFMA_B16(ax[k], bx_(2, k), au, 0, 0, 0);
            awx = MFMA_B16(ax[k], bx_(3, k), awx, 0, 0, 0);
        }
#pragma unroll
        for (int r = 0; r < 4; r++) {
            int idx = quad * 4 + r;
            if (idx < nv) {
                int node = base + idx;
                int ch = 2 * node + 1;
                float iv = sig_(ai[r] + bb[0]);
                float ov = sig_(ao[r] + bb[1]);
                float uv = tanh_(au[r] + bb[2]);
                float f0 = sig_(awx[r] + af0[r] + bb[3]);
                float f1 = sig_(awx[r] + af1[r] + bb[4]);
                float c0 = b2f_u(S[HC0 + ch * 136 + o]);
                float c1 = b2f_u(S[HC0 + (ch + 1) * 136 + o]);
                float cn = iv * uv + f0 * c0 + f1 * c1;
                float hn = ov * tanh_(cn);
                S[node * 136 + o] = f2b(hn);
                S[HC0 + node * 136 + o] = f2b(cn);
                if (isRoot) {
                    out[((size_t)l * 128 + tree) * 128 + o] = hn;
                    out[32768 + ((size_t)l * 128 + tree) * 128 + o] = cn;
                }
            }
        }
    };

    // ---- interval 1: all 8 d7 tiles (independent; children from global) ----
#pragma unroll 2
    for (int t = 0; t < 8; t++) itile_g(t);
    BARLDS();
    // ---- interval 2: d6 (4 tiles) ----
#pragma unroll 2
    for (int t = 0; t < 4; t++) itile_l(63 + 16 * t, 16, false);
    BARLDS();
    // ---- interval 3: d5 (2 tiles) ----
    itile_l(31, 16, false);
    itile_l(47, 16, false);
    BARLDS();
    // ---- intervals 4..8: d4..d0 ----
    itile_l(15, 16, false);
    BARLDS();
    itile_l(7, 8, false);
    BARLDS();
    itile_l(3, 4, false);
    BARLDS();
    itile_l(1, 2, false);
    BARLDS();
    itile_l(0, 1, true);
}

extern "C" void kernel_launch(void* const* d_in, const int* in_sizes, int n_in,
                              void* d_out, int out_size, void* d_ws, size_t ws_size,
                              hipStream_t stream) {
    const float* feat = (const float*)d_in[0];
    const float* Wiou = (const float*)d_in[1];
    const float* biou = (const float*)d_in[2];
    const float* Uiou = (const float*)d_in[3];
    const float* Wf   = (const float*)d_in[4];
    const float* bfv  = (const float*)d_in[5];
    const float* Uf   = (const float*)d_in[6];
    float* out = (float*)d_out;

    // ws (bf16 shorts): BgU[131072] BgX[131072] xb[4177920] hb[8388608]
    //   cb[8388608] + bp5(f32)[1280]  ~= 42.4 MB
    unsigned short* BgU = (unsigned short*)d_ws;
    unsigned short* BgX = BgU + (size_t)131072;
    unsigned short* xb16 = BgX + (size_t)131072;
    unsigned short* hb = xb16 + (size_t)4177920;
    unsigned short* cb = hb + (size_t)8388608;
    float* bp5 = (float*)(cb + (size_t)8388608);

    pack_b<<<3064, 256, 0, stream>>>(Wiou, biou, Uiou, Wf, bfv, Uf, feat,
                                     BgU, BgX, bp5, xb16);
    leafwx<<<2048, 256, 0, stream>>>(feat, BgX, bp5, hb, cb);
    forest<<<256, 512, 0, stream>>>(xb16, hb, cb, BgU, BgX, bp5, out);
}